// Round 9
// baseline (281.283 us; speedup 1.0000x reference)
//
#include <hip/hip_runtime.h>
#include <hip/hip_bf16.h>
#include <math.h>

// SparseMLP: W=8 experts, per w: out = gelu(X @ W1 + b1) @ W2 + b2
// Round 9: R4 base (8-phase 256x256x64, 8 waves, counted vmcnt(4), XOR-
// swizzled LDS via pre-swizzled gload source, expert->XCD pinning). X
// f32->bf16 convert fused into GEMM1 A-staging (R8), but with the cvt +
// ds_write moved 2 phases EARLIER (ph2/ph6 instead of ph4/ph8) so the
// consuming phase's lgkmcnt(0) never stalls on the A-write drain.
// Steady-state vmcnt ledger (A_F32 path):
//   iter start: B(t+1)[8] outstanding
//   ph1: +A(t+1)[8]        ph2: +B(t+2,0)[4]; vmcnt(4) drains B(t+1)+A(t+1);
//                                A_WRITES(nxt)  (drains at ph3 lgkm, 2
//                                barriers before ph5's reads)
//   ph3: +B(t+2,1)[4]      ph4: (empty)
//   ph5: +A(t+2)[8]        ph6: +B(t+3,0)[4]; vmcnt(4) drains B(t+2)+A(t+2);
//                                A_WRITES(cur)
//   ph7: +B(t+3,1)[4]      ph8: (empty)  -> end: B(t+3)[8] = invariant
// GEMM2 keeps the R4 gload_lds A-path (A_F32=false). Weight prep = R4.

typedef float f32x4 __attribute__((ext_vector_type(4)));
typedef short bf16x8 __attribute__((ext_vector_type(8)));
typedef short bf16x4 __attribute__((ext_vector_type(4)));
typedef unsigned short u16;

#define NW 8
#define MDIM 2048   // BHS*SEQ
#define HDIM 2048
#define FFN  1024

static __device__ __forceinline__ u16 f32_to_bf16_rn(float f) {
  union { float f; unsigned u; } v; v.f = f;
  unsigned r = v.u + 0x7FFF + ((v.u >> 16) & 1);
  return (u16)(r >> 16);
}

static __device__ __forceinline__ void gload_lds16(const void* g, void* l) {
  __builtin_amdgcn_global_load_lds(
      (const __attribute__((address_space(1))) void*)g,
      (__attribute__((address_space(3))) void*)l, 16, 0, 0);
}

// in: (NW, R, C) f32 -> out: (NW, C, R) bf16 (convert + transpose), 64x64 tile
__global__ void convert_transpose_kernel(const float* __restrict__ in,
                                         u16* __restrict__ out, int R, int C) {
  __shared__ u16 tile[64][68];
  int w = blockIdx.z;
  int c0 = blockIdx.x * 64, r0 = blockIdx.y * 64;
  int t = threadIdx.x;  // 256 threads
  const float* ip = in + (size_t)w * R * C;
  u16* op = out + (size_t)w * C * R;
  int tr = t >> 4;       // 0..15
  int tc4 = (t & 15) * 4;
#pragma unroll
  for (int j = 0; j < 4; ++j) {
    int r = tr + j * 16;
    f32x4 v = *(const f32x4*)(ip + (size_t)(r0 + r) * C + c0 + tc4);
    tile[r][tc4 + 0] = f32_to_bf16_rn(v.x);
    tile[r][tc4 + 1] = f32_to_bf16_rn(v.y);
    tile[r][tc4 + 2] = f32_to_bf16_rn(v.z);
    tile[r][tc4 + 3] = f32_to_bf16_rn(v.w);
  }
  __syncthreads();
#pragma unroll
  for (int j = 0; j < 4; ++j) {
    int c = tr + j * 16;
    bf16x4 p;
    p[0] = (short)tile[tc4 + 0][c];
    p[1] = (short)tile[tc4 + 1][c];
    p[2] = (short)tile[tc4 + 2][c];
    p[3] = (short)tile[tc4 + 3][c];
    *(bf16x4*)(op + (size_t)(c0 + c) * R + r0 + tc4) = p;
  }
}

// ---------------- GEMM ----------------
// LDS layout per K-tile buffer (64KB): A0 @0, A1 @16384, B0 @32768, B1 @49152
#define STAGE_AH(dst, tt, h)                                                  \
  do {                                                                        \
    gload_lds16(gA + (size_t)(h) * 128 * rowK + (size_t)(tt) * 128,           \
                (dst) + (h) * 16384 + tid * 16);                              \
    gload_lds16(gA + ((size_t)(h) * 128 + 64) * rowK + (size_t)(tt) * 128,    \
                (dst) + (h) * 16384 + 8192 + tid * 16);                       \
  } while (0)
#define STAGE_BH(dst, tt, h)                                                  \
  do {                                                                        \
    gload_lds16(gB + (size_t)(h) * 128 * rowK + (size_t)(tt) * 128,           \
                (dst) + 32768 + (h) * 16384 + tid * 16);                      \
    gload_lds16(gB + ((size_t)(h) * 128 + 64) * rowK + (size_t)(tt) * 128,    \
                (dst) + 32768 + (h) * 16384 + 8192 + tid * 16);               \
  } while (0)

// A_F32 path: issue 8 f32x4 loads for A-tile tt (rows h*128+g*64+r8,
// f32 bytes [2*csw, 2*csw+32) -> same bf16 slots as gload path)
#define A_LOADS(tt)                                                           \
  _Pragma("unroll") for (int h_ = 0; h_ < 2; ++h_)                            \
  _Pragma("unroll") for (int g_ = 0; g_ < 2; ++g_)                            \
  _Pragma("unroll") for (int j_ = 0; j_ < 2; ++j_)                            \
      ar[h_][g_][j_] = *(const f32x4*)(gAf +                                  \
          (size_t)(h_ * 128 + g_ * 64) * rowKf + (size_t)(tt) * 256 + j_ * 16)

#define A_WRITES(dst)                                                         \
  _Pragma("unroll") for (int h_ = 0; h_ < 2; ++h_)                            \
  _Pragma("unroll") for (int g_ = 0; g_ < 2; ++g_) {                          \
    bf16x8 p_;                                                                \
    _Pragma("unroll") for (int e_ = 0; e_ < 4; ++e_) {                        \
      p_[e_]     = (short)f32_to_bf16_rn(ar[h_][g_][0][e_]);                  \
      p_[e_ + 4] = (short)f32_to_bf16_rn(ar[h_][g_][1][e_]);                  \
    }                                                                         \
    *(bf16x8*)((dst) + h_ * 16384 + g_ * 8192 + tid * 16) = p_;               \
  }

#define DO_PHASE(SB, q, first, STAGES, VMCODE)                                \
  {                                                                           \
    if (first) {                                                              \
      _Pragma("unroll") for (int jj = 0; jj < 4; ++jj)                        \
          _Pragma("unroll") for (int kk = 0; kk < 2; ++kk)                    \
              bfr[jj][kk] = *(const bf16x8*)((SB) + Boff +                    \
                  (brow + jj * 16 + ra) * 128 + (colsw ^ (kk << 6)));         \
    }                                                                         \
    _Pragma("unroll") for (int ii = 0; ii < 2; ++ii)                          \
        _Pragma("unroll") for (int kk = 0; kk < 2; ++kk)                      \
            afr[ii][kk] = *(const bf16x8*)((SB) + Aoff +                      \
                ((q)*32 + ii * 16 + ra) * 128 + (colsw ^ (kk << 6)));         \
    STAGES;                                                                   \
    __builtin_amdgcn_s_barrier();                                             \
    asm volatile("s_waitcnt lgkmcnt(0)" ::: "memory");                        \
    __builtin_amdgcn_sched_barrier(0);                                        \
    __builtin_amdgcn_s_setprio(1);                                            \
    _Pragma("unroll") for (int ii = 0; ii < 2; ++ii)                          \
        _Pragma("unroll") for (int jj = 0; jj < 4; ++jj)                      \
            _Pragma("unroll") for (int kk = 0; kk < 2; ++kk)                  \
                acc[(q)*2 + ii][jj] =                                         \
                    __builtin_amdgcn_mfma_f32_16x16x32_bf16(                  \
                        afr[ii][kk], bfr[jj][kk], acc[(q)*2 + ii][jj],        \
                        0, 0, 0);                                             \
    __builtin_amdgcn_s_setprio(0);                                            \
    VMCODE;                                                                   \
    __builtin_amdgcn_s_barrier();                                             \
  }

template <bool A_F32, bool GELU, bool C_F32>
__global__ __launch_bounds__(512, 2) void mlp_gemm(
    const void* __restrict__ Aptr, const u16* __restrict__ Bt,
    const float* __restrict__ bias, void* __restrict__ Cptr,
    int M, int N, int K, int nN) {
  __shared__ __align__(16) char lds[131072];
  char* cur = lds;
  char* nxt = lds + 65536;

  const int bid = blockIdx.x;
  const int w = bid & 7;            // expert -> pinned to XCD bid%8
  const int jb = bid >> 3;
  const int m0 = (jb / nN) * 256;
  const int n0 = (jb % nN) * 256;

  const int tid = threadIdx.x;
  const int wid = tid >> 6, lane = tid & 63;
  const int wr = wid >> 2, wc = wid & 3;   // 2 M-waves x 4 N-waves
  const int qa = lane >> 4, ra = lane & 15;

  const u16* btp = Bt + (size_t)w * N * K;
  const float* bp = bias + (size_t)w * N;

  const size_t rowK = (size_t)K * 2;
  const size_t rowKf = (size_t)K * 4;
  const int r8 = tid >> 3;
  const int csw = ((tid & 7) * 16) ^ ((r8 & 7) << 4);
  // bf16 A source (A_F32=false)
  const char* gA = (const char*)((const u16*)Aptr + (size_t)w * M * K) +
                   (size_t)(m0 + r8) * rowK + csw;
  // f32 A source (A_F32=true): f32 byte offset = 2 * bf16 byte offset
  const char* gAf = (const char*)((const float*)Aptr + (size_t)w * M * K) +
                    (size_t)(m0 + r8) * rowKf + 2 * csw;
  const char* gB = (const char*)btp + (size_t)(n0 + r8) * rowK + csw;

  const int colsw = (qa * 16) ^ ((ra & 7) << 4);
  const int Aoff = wr * 16384;
  const int Boff = 32768 + (wc >> 1) * 16384;
  const int brow = (wc & 1) * 64;

  f32x4 acc[8][4];
#pragma unroll
  for (int i = 0; i < 8; ++i)
#pragma unroll
    for (int j = 0; j < 4; ++j)
#pragma unroll
      for (int r = 0; r < 4; ++r) acc[i][j][r] = 0.0f;

  const int NT = K >> 6;        // even for both GEMMs
  const int nIter = NT >> 1;

  bf16x8 bfr[4][2], afr[2][2];
  f32x4 ar[2][2][2];

  if (A_F32) {
    // prologue: A(0) f32 loads [8], B(0) [8], B(1) [8] = 24 outstanding;
    // vmcnt(8) drains A(0)+B(0), leaves B(1)[8] = steady-state invariant.
    A_LOADS(0);
    STAGE_BH(cur, 0, 0); STAGE_BH(cur, 0, 1);
    STAGE_BH(nxt, 1, 0); STAGE_BH(nxt, 1, 1);
    asm volatile("s_waitcnt vmcnt(8)" ::: "memory");
    A_WRITES(cur);
    asm volatile("s_waitcnt lgkmcnt(0)" ::: "memory");
    __builtin_amdgcn_sched_barrier(0);
    __builtin_amdgcn_s_barrier();

    for (int it = 0; it < nIter; ++it) {
      const int t = it * 2;
      const bool s2 = (t + 2) < NT;   // NT even => (t+3)<NT iff s2

      DO_PHASE(cur, 0, 1, { A_LOADS(t + 1); }, {});
      DO_PHASE(cur, 1, 0, { if (s2) STAGE_BH(cur, t + 2, 0); }, {
        if (s2) asm volatile("s_waitcnt vmcnt(4)" ::: "memory");
        else    asm volatile("s_waitcnt vmcnt(0)" ::: "memory");
        A_WRITES(nxt);                 // A(t+1) -> nxt (read at ph5)
        __builtin_amdgcn_sched_barrier(0);
      });
      DO_PHASE(cur, 2, 0, { if (s2) STAGE_BH(cur, t + 2, 1); }, {});
      DO_PHASE(cur, 3, 0, {}, {});
      DO_PHASE(nxt, 0, 1, { if (s2) A_LOADS(t + 2); }, {});
      DO_PHASE(nxt, 1, 0, { if (s2) STAGE_BH(nxt, t + 3, 0); }, {
        if (s2) {
          asm volatile("s_waitcnt vmcnt(4)" ::: "memory");
          A_WRITES(cur);               // A(t+2) -> cur (read next iter ph1)
          __builtin_amdgcn_sched_barrier(0);
        }
      });
      DO_PHASE(nxt, 2, 0, { if (s2) STAGE_BH(nxt, t + 3, 1); }, {});
      DO_PHASE(nxt, 3, 0, {}, {});
    }
  } else {
    STAGE_BH(cur, 0, 0); STAGE_BH(cur, 0, 1);
    STAGE_AH(cur, 0, 0); STAGE_AH(cur, 0, 1);
    STAGE_BH(nxt, 1, 0); STAGE_BH(nxt, 1, 1);
    asm volatile("s_waitcnt vmcnt(4)" ::: "memory");
    __builtin_amdgcn_sched_barrier(0);
    __builtin_amdgcn_s_barrier();

    for (int it = 0; it < nIter; ++it) {
      const int t = it * 2;
      const bool s2 = (t + 2) < NT, s3 = (t + 3) < NT;

      DO_PHASE(cur, 0, 1, { STAGE_AH(nxt, t + 1, 0); }, {});
      DO_PHASE(cur, 1, 0,
               { STAGE_AH(nxt, t + 1, 1); if (s2) STAGE_BH(cur, t + 2, 0); }, {});
      DO_PHASE(cur, 2, 0, { if (s2) STAGE_BH(cur, t + 2, 1); }, {});
      DO_PHASE(cur, 3, 0, {}, {
        if (s2) asm volatile("s_waitcnt vmcnt(4)" ::: "memory");
        else    asm volatile("s_waitcnt vmcnt(0)" ::: "memory");
        __builtin_amdgcn_sched_barrier(0);
      });
      DO_PHASE(nxt, 0, 1, { if (s2) STAGE_AH(cur, t + 2, 0); }, {});
      DO_PHASE(nxt, 1, 0,
               { if (s2) STAGE_AH(cur, t + 2, 1); if (s3) STAGE_BH(nxt, t + 3, 0); }, {});
      DO_PHASE(nxt, 2, 0, { if (s3) STAGE_BH(nxt, t + 3, 1); }, {});
      DO_PHASE(nxt, 3, 0, {}, {
        if (s3) asm volatile("s_waitcnt vmcnt(4)" ::: "memory");
        else    asm volatile("s_waitcnt vmcnt(0)" ::: "memory");
        __builtin_amdgcn_sched_barrier(0);
      });
    }
  }

  // epilogue: + bias, optional exact GELU, store
#pragma unroll
  for (int i = 0; i < 8; ++i) {
#pragma unroll
    for (int j = 0; j < 4; ++j) {
      int col = n0 + wc * 64 + j * 16 + ra;
      float bv = bp[col];
#pragma unroll
      for (int r = 0; r < 4; ++r) {
        int row = m0 + wr * 128 + i * 16 + qa * 4 + r;
        float v = acc[i][j][r] + bv;
        if (GELU) v = 0.5f * v * (1.0f + erff(v * 0.70710678118654752f));
        if (C_F32)
          ((float*)Cptr)[(size_t)w * M * N + (size_t)row * N + col] = v;
        else
          ((u16*)Cptr)[(size_t)w * M * N + (size_t)row * N + col] =
              f32_to_bf16_rn(v);
      }
    }
  }
}

__global__ void bias_out_kernel(const float* __restrict__ b2,
                                float* __restrict__ outb) {
  int i = blockIdx.x * 256 + threadIdx.x;
  if (i < NW * HDIM) outb[i] = b2[i];
}

extern "C" void kernel_launch(void* const* d_in, const int* in_sizes, int n_in,
                              void* d_out, int out_size, void* d_ws,
                              size_t ws_size, hipStream_t stream) {
  const float* hs = (const float*)d_in[0];  // (8,2,1024,2048) f32
  const float* w1 = (const float*)d_in[1];  // (8,2048,1024) f32
  const float* b1 = (const float*)d_in[2];  // (8,1,1024) f32
  const float* w2 = (const float*)d_in[3];  // (8,1024,2048) f32
  const float* b2 = (const float*)d_in[4];  // (8,2048) f32

  // ws (u16): W1t (8,1024,2048) | W2t (8,2048,1024) | inter (8,2048,1024)
  u16* W1t = (u16*)d_ws;
  u16* W2t = W1t + (size_t)NW * FFN * HDIM;
  u16* inter = W2t + (size_t)NW * HDIM * FFN;

  // w1 (R=HDIM, C=FFN) -> W1t (FFN, HDIM)
  convert_transpose_kernel<<<dim3(FFN / 64, HDIM / 64, NW), 256, 0, stream>>>(
      w1, W1t, HDIM, FFN);
  // w2 (R=FFN, C=HDIM) -> W2t (HDIM, FFN)
  convert_transpose_kernel<<<dim3(HDIM / 64, FFN / 64, NW), 256, 0, stream>>>(
      w2, W2t, FFN, HDIM);

  // inter = gelu(X @ W1 + b1)  [bf16]  A = X in f32, cvt fused into staging
  mlp_gemm<true, true, false>
      <<<dim3(NW * (MDIM / 256) * (FFN / 256)), 512, 0, stream>>>(
          hs, W1t, b1, inter, MDIM, FFN, HDIM, FFN / 256);
  // out = inter @ W2 + b2  [f32]  A = inter bf16 (gload_lds path)
  mlp_gemm<false, false, true>
      <<<dim3(NW * (MDIM / 256) * (HDIM / 256)), 512, 0, stream>>>(
          inter, W2t, b2, d_out, MDIM, HDIM, FFN, HDIM / 256);

  float* outb = (float*)d_out + (size_t)NW * MDIM * HDIM;
  bias_out_kernel<<<dim3((NW * HDIM + 255) / 256), 256, 0, stream>>>(b2, outb);
}

// Round 10
// 231.619 us; speedup vs baseline: 1.2144x; 1.2144x over previous
//
#include <hip/hip_runtime.h>
#include <hip/hip_bf16.h>
#include <math.h>

// SparseMLP: W=8 experts, per w: out = gelu(X @ W1 + b1) @ W2 + b2
// Round 10: R4 base restored (8-phase 256x256x64, 8 waves, counted vmcnt(4),
// XOR-swizzled LDS via pre-swizzled gload source, expert->XCD pinning,
// separate X-convert prepass — the R8/R9 fused-convert line is abandoned:
// reg-staging costs ~16% vs global_load_lds, matching the guide's T14 note).
// NEW vs R4 (register-only change, sync structure untouched):
//   * frag ds_reads PIPELINED one phase ahead into ping-pong buffers
//     (afrA/afrB per-phase A-frags, bfrA/bfrB per-K-tile B-frags, all
//     statically indexed). Prefetch sits AFTER the phase's vmcnt/setprio(0)
//     and BEFORE its end barrier, so:
//       - ph4 prefetch of nxt(t+1) follows vmcnt(4) that drains A/B(t+1);
//       - ph8 prefetch of cur(t+2) follows vmcnt(4) that drains A/B(t+2);
//       - every wave's prefetch completes at its next lgkmcnt(0), one full
//         barrier before any wave can issue the stage that overwrites it.
//     Next phase's critical path = barrier + MFMA (read latency hidden).
//   * bias_out merged into the convert dispatch (one fewer launch).

typedef float f32x4 __attribute__((ext_vector_type(4)));
typedef short bf16x8 __attribute__((ext_vector_type(8)));
typedef short bf16x4 __attribute__((ext_vector_type(4)));
typedef unsigned short u16;

#define NW 8
#define MDIM 2048   // BHS*SEQ
#define HDIM 2048
#define FFN  1024

static __device__ __forceinline__ u16 f32_to_bf16_rn(float f) {
  union { float f; unsigned u; } v; v.f = f;
  unsigned r = v.u + 0x7FFF + ((v.u >> 16) & 1);
  return (u16)(r >> 16);
}

static __device__ __forceinline__ void gload_lds16(const void* g, void* l) {
  __builtin_amdgcn_global_load_lds(
      (const __attribute__((address_space(1))) void*)g,
      (__attribute__((address_space(3))) void*)l, 16, 0, 0);
}

// X (NW*MDIM*HDIM f32) -> bf16 (4 f32/thread) + out_bias tail (last 16 blocks)
__global__ void convert_bf16_kernel(const float* __restrict__ in,
                                    u16* __restrict__ out,
                                    const float* __restrict__ b2,
                                    float* __restrict__ outb) {
  int bid = blockIdx.x;
  if (bid >= NW * MDIM * HDIM / 4 / 256) {  // bias tail
    int i = (bid - NW * MDIM * HDIM / 4 / 256) * 256 + threadIdx.x;
    if (i < NW * HDIM) outb[i] = b2[i];
    return;
  }
  size_t i = (size_t)bid * blockDim.x + threadIdx.x;  // f32x4 index
  f32x4 v = ((const f32x4*)in)[i];
  bf16x4 p;
  p[0] = (short)f32_to_bf16_rn(v.x);
  p[1] = (short)f32_to_bf16_rn(v.y);
  p[2] = (short)f32_to_bf16_rn(v.z);
  p[3] = (short)f32_to_bf16_rn(v.w);
  ((bf16x4*)out)[i] = p;
}

// in: (NW, R, C) f32 -> out: (NW, C, R) bf16 (convert + transpose), 64x64 tile
__global__ void convert_transpose_kernel(const float* __restrict__ in,
                                         u16* __restrict__ out, int R, int C) {
  __shared__ u16 tile[64][68];
  int w = blockIdx.z;
  int c0 = blockIdx.x * 64, r0 = blockIdx.y * 64;
  int t = threadIdx.x;  // 256 threads
  const float* ip = in + (size_t)w * R * C;
  u16* op = out + (size_t)w * C * R;
  int tr = t >> 4;       // 0..15
  int tc4 = (t & 15) * 4;
#pragma unroll
  for (int j = 0; j < 4; ++j) {
    int r = tr + j * 16;
    f32x4 v = *(const f32x4*)(ip + (size_t)(r0 + r) * C + c0 + tc4);
    tile[r][tc4 + 0] = f32_to_bf16_rn(v.x);
    tile[r][tc4 + 1] = f32_to_bf16_rn(v.y);
    tile[r][tc4 + 2] = f32_to_bf16_rn(v.z);
    tile[r][tc4 + 3] = f32_to_bf16_rn(v.w);
  }
  __syncthreads();
#pragma unroll
  for (int j = 0; j < 4; ++j) {
    int c = tr + j * 16;
    bf16x4 p;
    p[0] = (short)tile[tc4 + 0][c];
    p[1] = (short)tile[tc4 + 1][c];
    p[2] = (short)tile[tc4 + 2][c];
    p[3] = (short)tile[tc4 + 3][c];
    *(bf16x4*)(op + (size_t)(c0 + c) * R + r0 + tc4) = p;
  }
}

// ---------------- GEMM ----------------
// LDS layout per K-tile buffer (64KB): A0 @0, A1 @16384, B0 @32768, B1 @49152
#define STAGE_AH(dst, tt, h)                                                  \
  do {                                                                        \
    gload_lds16(gA + (size_t)(h) * 128 * rowK + (size_t)(tt) * 128,           \
                (dst) + (h) * 16384 + tid * 16);                              \
    gload_lds16(gA + ((size_t)(h) * 128 + 64) * rowK + (size_t)(tt) * 128,    \
                (dst) + (h) * 16384 + 8192 + tid * 16);                       \
  } while (0)
#define STAGE_BH(dst, tt, h)                                                  \
  do {                                                                        \
    gload_lds16(gB + (size_t)(h) * 128 * rowK + (size_t)(tt) * 128,           \
                (dst) + 32768 + (h) * 16384 + tid * 16);                      \
    gload_lds16(gB + ((size_t)(h) * 128 + 64) * rowK + (size_t)(tt) * 128,    \
                (dst) + 32768 + (h) * 16384 + 8192 + tid * 16);               \
  } while (0)

// fragment prefetch (into named ping-pong buffers; all indices static)
#define LOAD_A(DST, SB, q)                                                    \
  _Pragma("unroll") for (int ii = 0; ii < 2; ++ii)                            \
      _Pragma("unroll") for (int kk = 0; kk < 2; ++kk)                        \
          DST[ii][kk] = *(const bf16x8*)((SB) + Aoff +                        \
              ((q)*32 + ii * 16 + ra) * 128 + (colsw ^ (kk << 6)))
#define LOAD_B(DST, SB)                                                       \
  _Pragma("unroll") for (int jj = 0; jj < 4; ++jj)                            \
      _Pragma("unroll") for (int kk = 0; kk < 2; ++kk)                        \
          DST[jj][kk] = *(const bf16x8*)((SB) + Boff +                        \
              (brow + jj * 16 + ra) * 128 + (colsw ^ (kk << 6)))

// phase q: MFMA on preloaded frags AF/BF; STAGES before barrier; VMCODE
// (counted vmcnt) after MFMA; PREFETCH (next phase's frags) after VMCODE.
#define DO_PHASE(q, AF, BF, STAGES, VMCODE, PREFETCH)                         \
  {                                                                           \
    STAGES;                                                                   \
    __builtin_amdgcn_s_barrier();                                             \
    asm volatile("s_waitcnt lgkmcnt(0)" ::: "memory");                        \
    __builtin_amdgcn_sched_barrier(0);                                        \
    __builtin_amdgcn_s_setprio(1);                                            \
    _Pragma("unroll") for (int ii = 0; ii < 2; ++ii)                          \
        _Pragma("unroll") for (int jj = 0; jj < 4; ++jj)                      \
            _Pragma("unroll") for (int kk = 0; kk < 2; ++kk)                  \
                acc[(q)*2 + ii][jj] =                                         \
                    __builtin_amdgcn_mfma_f32_16x16x32_bf16(                  \
                        AF[ii][kk], BF[jj][kk], acc[(q)*2 + ii][jj],          \
                        0, 0, 0);                                             \
    __builtin_amdgcn_s_setprio(0);                                            \
    VMCODE;                                                                   \
    PREFETCH;                                                                 \
    __builtin_amdgcn_sched_barrier(0);                                        \
    __builtin_amdgcn_s_barrier();                                             \
  }

template <bool GELU, bool C_F32>
__global__ __launch_bounds__(512, 2) void mlp_gemm(
    const u16* __restrict__ A, const u16* __restrict__ Bt,
    const float* __restrict__ bias, void* __restrict__ Cptr,
    int M, int N, int K, int nN) {
  __shared__ __align__(16) char lds[131072];
  char* cur = lds;
  char* nxt = lds + 65536;

  const int bid = blockIdx.x;
  const int w = bid & 7;            // expert -> pinned to XCD bid%8
  const int jb = bid >> 3;
  const int m0 = (jb / nN) * 256;
  const int n0 = (jb % nN) * 256;

  const int tid = threadIdx.x;
  const int wid = tid >> 6, lane = tid & 63;
  const int wr = wid >> 2, wc = wid & 3;   // 2 M-waves x 4 N-waves
  const int qa = lane >> 4, ra = lane & 15;

  const u16* ap = A + (size_t)w * M * K;
  const u16* btp = Bt + (size_t)w * N * K;
  const float* bp = bias + (size_t)w * N;

  const size_t rowK = (size_t)K * 2;
  const int r8 = tid >> 3;
  const int csw = ((tid & 7) * 16) ^ ((r8 & 7) << 4);
  const char* gA = (const char*)ap + (size_t)(m0 + r8) * rowK + csw;
  const char* gB = (const char*)btp + (size_t)(n0 + r8) * rowK + csw;

  const int colsw = (qa * 16) ^ ((ra & 7) << 4);
  const int Aoff = wr * 16384;
  const int Boff = 32768 + (wc >> 1) * 16384;
  const int brow = (wc & 1) * 64;

  f32x4 acc[8][4];
#pragma unroll
  for (int i = 0; i < 8; ++i)
#pragma unroll
    for (int j = 0; j < 4; ++j)
#pragma unroll
      for (int r = 0; r < 4; ++r) acc[i][j][r] = 0.0f;

  const int NT = K >> 6;        // even for both GEMMs
  const int nIter = NT >> 1;

  // prologue: tile0 (cur) fully + tile1 (nxt) B-halves; 12 loads/thread
  STAGE_BH(cur, 0, 0); STAGE_BH(cur, 0, 1);
  STAGE_AH(cur, 0, 0); STAGE_AH(cur, 0, 1);
  STAGE_BH(nxt, 1, 0); STAGE_BH(nxt, 1, 1);
  asm volatile("s_waitcnt vmcnt(4)" ::: "memory");  // tile0 landed; B(1) fly
  __builtin_amdgcn_sched_barrier(0);
  __builtin_amdgcn_s_barrier();

  bf16x8 afrA[2][2], afrB[2][2], bfrA[4][2], bfrB[4][2];
  // preload iter-0 ph1 fragments (tile0 resident)
  LOAD_B(bfrA, cur);
  LOAD_A(afrA, cur, 0);
  __builtin_amdgcn_sched_barrier(0);

  for (int it = 0; it < nIter; ++it) {
    const int t = it * 2;
    const bool s2 = (t + 2) < NT;   // NT even => (t+3)<NT iff s2

    // ---- K-tile t (cur); consumers q0..q3 use afrA/afrB alternating ----
    DO_PHASE(0, afrA, bfrA, { STAGE_AH(nxt, t + 1, 0); }, {},
             { LOAD_A(afrB, cur, 1); });
    DO_PHASE(1, afrB, bfrA,
             { STAGE_AH(nxt, t + 1, 1); if (s2) STAGE_BH(cur, t + 2, 0); }, {},
             { LOAD_A(afrA, cur, 2); });
    DO_PHASE(2, afrA, bfrA, { if (s2) STAGE_BH(cur, t + 2, 1); }, {},
             { LOAD_A(afrB, cur, 3); });
    DO_PHASE(3, afrB, bfrA, {}, {
      if (s2) asm volatile("s_waitcnt vmcnt(4)" ::: "memory");
      else    asm volatile("s_waitcnt vmcnt(0)" ::: "memory");
      __builtin_amdgcn_sched_barrier(0);
    }, { LOAD_B(bfrB, nxt); LOAD_A(afrA, nxt, 0); });  // t+1 drained above

    // ---- K-tile t+1 (nxt) ----
    DO_PHASE(0, afrA, bfrB, { if (s2) STAGE_AH(cur, t + 2, 0); }, {},
             { LOAD_A(afrB, nxt, 1); });
    DO_PHASE(1, afrB, bfrB,
             { if (s2) STAGE_AH(cur, t + 2, 1); if (s2) STAGE_BH(nxt, t + 3, 0); }, {},
             { LOAD_A(afrA, nxt, 2); });
    DO_PHASE(2, afrA, bfrB, { if (s2) STAGE_BH(nxt, t + 3, 1); }, {},
             { LOAD_A(afrB, nxt, 3); });
    DO_PHASE(3, afrB, bfrB, {}, {
      if (s2) asm volatile("s_waitcnt vmcnt(4)" ::: "memory");
      else    asm volatile("s_waitcnt vmcnt(0)" ::: "memory");
      __builtin_amdgcn_sched_barrier(0);
    }, { LOAD_B(bfrA, cur); LOAD_A(afrA, cur, 0); });  // t+2 drained above
    // (last iter: this prefetch reads stale LDS; values are never consumed)
  }

  // epilogue: + bias, optional exact GELU, store
#pragma unroll
  for (int i = 0; i < 8; ++i) {
#pragma unroll
    for (int j = 0; j < 4; ++j) {
      int col = n0 + wc * 64 + j * 16 + ra;
      float bv = bp[col];
#pragma unroll
      for (int r = 0; r < 4; ++r) {
        int row = m0 + wr * 128 + i * 16 + qa * 4 + r;
        float v = acc[i][j][r] + bv;
        if (GELU) v = 0.5f * v * (1.0f + erff(v * 0.70710678118654752f));
        if (C_F32)
          ((float*)Cptr)[(size_t)w * M * N + (size_t)row * N + col] = v;
        else
          ((u16*)Cptr)[(size_t)w * M * N + (size_t)row * N + col] =
              f32_to_bf16_rn(v);
      }
    }
  }
}

extern "C" void kernel_launch(void* const* d_in, const int* in_sizes, int n_in,
                              void* d_out, int out_size, void* d_ws,
                              size_t ws_size, hipStream_t stream) {
  const float* hs = (const float*)d_in[0];  // (8,2,1024,2048) f32
  const float* w1 = (const float*)d_in[1];  // (8,2048,1024) f32
  const float* b1 = (const float*)d_in[2];  // (8,1,1024) f32
  const float* w2 = (const float*)d_in[3];  // (8,1024,2048) f32
  const float* b2 = (const float*)d_in[4];  // (8,2048) f32

  // ws (u16): W1t (8,1024,2048) | W2t (8,2048,1024) | inter (8,2048,1024) | Xb
  u16* W1t = (u16*)d_ws;
  u16* W2t = W1t + (size_t)NW * FFN * HDIM;
  u16* inter = W2t + (size_t)NW * HDIM * FFN;
  u16* XbWs = inter + (size_t)NW * MDIM * FFN;
  size_t need = ((size_t)NW * FFN * HDIM * 2 + (size_t)NW * MDIM * FFN +
                 (size_t)NW * MDIM * HDIM) * sizeof(u16);
  u16* Xb = (ws_size >= need) ? XbWs : (u16*)d_out;

  float* outb = (float*)d_out + (size_t)NW * MDIM * HDIM;

  // X -> bf16 (+ bias tail in the same dispatch)
  convert_bf16_kernel<<<dim3(NW * MDIM * HDIM / 4 / 256 + 16), 256, 0,
                        stream>>>(hs, Xb, b2, outb);
  // w1 (R=HDIM, C=FFN) -> W1t (FFN, HDIM)
  convert_transpose_kernel<<<dim3(FFN / 64, HDIM / 64, NW), 256, 0, stream>>>(
      w1, W1t, HDIM, FFN);
  // w2 (R=FFN, C=HDIM) -> W2t (HDIM, FFN)
  convert_transpose_kernel<<<dim3(HDIM / 64, FFN / 64, NW), 256, 0, stream>>>(
      w2, W2t, FFN, HDIM);

  // inter = gelu(X @ W1 + b1)  [bf16]  M=2048 N=1024 K=2048 -> 256 blocks
  mlp_gemm<true, false>
      <<<dim3(NW * (MDIM / 256) * (FFN / 256)), 512, 0, stream>>>(
          Xb, W1t, b1, inter, MDIM, FFN, HDIM, FFN / 256);
  // out = inter @ W2 + b2  [f32]  M=2048 N=2048 K=1024 -> 512 blocks
  mlp_gemm<false, true>
      <<<dim3(NW * (MDIM / 256) * (HDIM / 256)), 512, 0, stream>>>(
          inter, W2t, b2, d_out, MDIM, HDIM, FFN, HDIM / 256);
}